// Round 6
// baseline (1087.099 us; speedup 1.0000x reference)
//
#include <hip/hip_runtime.h>
#include <hip/hip_bf16.h>

typedef __attribute__((ext_vector_type(8))) short short8;
typedef __attribute__((ext_vector_type(4))) float float4v;

__device__ __forceinline__ float bf2f(ushort u) {
    union { unsigned int i; float f; } x; x.i = ((unsigned int)u) << 16; return x.f;
}
__device__ __forceinline__ ushort f2bf(float f) {
    union { float f; unsigned int i; } x; x.f = f;
    unsigned int i = x.i;
    unsigned int r = (i + 0x7fffu + ((i >> 16) & 1u)) >> 16;
    return (ushort)r;
}

// ---------------------------------------------------------------------------
// Transpose+cast: src [K][N] fp32 -> dst [N][K] bf16. grid (N/64, K/64, NSRC).
// ---------------------------------------------------------------------------
__global__ __launch_bounds__(256) void transpose4_f2b(const float* __restrict__ s0,
                                                      const float* __restrict__ s1,
                                                      const float* __restrict__ s2,
                                                      const float* __restrict__ s3,
                                                      ushort* __restrict__ dst,
                                                      int K, int N) {
    __shared__ ushort tile[64][68];
    const float* srcs[4] = {s0, s1, s2, s3};
    const float* src = srcs[blockIdx.z];
    ushort* d = dst + (size_t)blockIdx.z * K * N;
    const int t = threadIdx.x;
    const int n0 = blockIdx.x * 64, k0 = blockIdx.y * 64;
    const int tr = t >> 4, tc = (t & 15) * 4;
#pragma unroll
    for (int i = 0; i < 4; ++i) {
        int row = tr + i * 16;
        float4 v = *(const float4*)&src[(size_t)(k0 + row) * N + n0 + tc];
        tile[row][tc + 0] = f2bf(v.x);
        tile[row][tc + 1] = f2bf(v.y);
        tile[row][tc + 2] = f2bf(v.z);
        tile[row][tc + 3] = f2bf(v.w);
    }
    __syncthreads();
#pragma unroll
    for (int i = 0; i < 4; ++i) {
        int n = tr + i * 16;
        ushort4 v;
        v.x = tile[tc + 0][n]; v.y = tile[tc + 1][n];
        v.z = tile[tc + 2][n]; v.w = tile[tc + 3][n];
        *(ushort4*)&d[(size_t)(n0 + n) * K + k0 + tc] = v;
    }
}

// ---------------------------------------------------------------------------
// Embed: h[2048][1024] fp32 = x[2048][64] @ emb_w[64][1024] + emb_b (all fp32)
// ---------------------------------------------------------------------------
__global__ __launch_bounds__(256) void embed_k(const float* __restrict__ x,
                                               const float* __restrict__ w,
                                               const float* __restrict__ b,
                                               float* __restrict__ h) {
    const int row = blockIdx.y;
    const int col = blockIdx.x * 256 + threadIdx.x;
    float acc = b[col];
#pragma unroll 8
    for (int k = 0; k < 64; ++k)
        acc += x[row * 64 + k] * w[k * 1024 + col];
    h[(size_t)row * 1024 + col] = acc;
}

// ---------------------------------------------------------------------------
// RMSNorm: fp32 h row, fp32 weight, bf16 out. grid 2048, 256 thr
// ---------------------------------------------------------------------------
__global__ __launch_bounds__(256) void rmsnorm_k(const float* __restrict__ h,
                                                 const float* __restrict__ w,
                                                 ushort* __restrict__ out) {
    const int row = blockIdx.x, t = threadIdx.x;
    float4 v = ((const float4*)(h + (size_t)row * 1024))[t];
    float ss = v.x * v.x + v.y * v.y + v.z * v.z + v.w * v.w;
#pragma unroll
    for (int off = 32; off > 0; off >>= 1) ss += __shfl_down(ss, off);
    __shared__ float red[4];
    if ((t & 63) == 0) red[t >> 6] = ss;
    __syncthreads();
    float inv = rsqrtf((red[0] + red[1] + red[2] + red[3]) * (1.0f / 1024.0f) + 1e-5f);
    float4 wv = ((const float4*)w)[t];
    ushort4 ov;
    ov.x = f2bf(v.x * inv * wv.x);
    ov.y = f2bf(v.y * inv * wv.y);
    ov.z = f2bf(v.z * inv * wv.z);
    ov.w = f2bf(v.w * inv * wv.w);
    *(ushort4*)&out[(size_t)row * 1024 + t * 4] = ov;
}

// ---------------------------------------------------------------------------
// Fused split-K reduce + residual add + RMSNorm.
// p: bf16 partials [4][2048][1024]. h += sum_z p; out = rmsnorm(h)*w (bf16).
// grid 2048, 256 thr.
// ---------------------------------------------------------------------------
__global__ __launch_bounds__(256) void reduce_rms_k(const ushort* __restrict__ p,
                                                    float* __restrict__ h,
                                                    const float* __restrict__ w,
                                                    ushort* __restrict__ out) {
    const int row = blockIdx.x, t = threadIdx.x;
    const int c = t * 4;
    size_t base = (size_t)row * 1024 + c;
    float a0 = 0, a1 = 0, a2 = 0, a3 = 0;
#pragma unroll
    for (int z = 0; z < 4; ++z) {
        ushort4 v = *(const ushort4*)&p[base + (size_t)z * 2048 * 1024];
        a0 += bf2f(v.x); a1 += bf2f(v.y); a2 += bf2f(v.z); a3 += bf2f(v.w);
    }
    float4 cur = *(float4*)&h[base];
    cur.x += a0; cur.y += a1; cur.z += a2; cur.w += a3;
    *(float4*)&h[base] = cur;
    float ss = cur.x * cur.x + cur.y * cur.y + cur.z * cur.z + cur.w * cur.w;
#pragma unroll
    for (int off = 32; off > 0; off >>= 1) ss += __shfl_down(ss, off);
    __shared__ float red[4];
    if ((t & 63) == 0) red[t >> 6] = ss;
    __syncthreads();
    float inv = rsqrtf((red[0] + red[1] + red[2] + red[3]) * (1.0f / 1024.0f) + 1e-5f);
    float4 wv = ((const float4*)w)[t];
    ushort4 ov;
    ov.x = f2bf(cur.x * inv * wv.x);
    ov.y = f2bf(cur.y * inv * wv.y);
    ov.z = f2bf(cur.z * inv * wv.z);
    ov.w = f2bf(cur.w * inv * wv.w);
    *(ushort4*)&out[base] = ov;
}

// ---------------------------------------------------------------------------
// RoPE tables: cos/sin [2048][32] fp32. grid 256, 256 thr
// ---------------------------------------------------------------------------
__global__ __launch_bounds__(256) void rope_table_k(float* __restrict__ ct,
                                                    float* __restrict__ st) {
    int idx = blockIdx.x * 256 + threadIdx.x;  // < 65536
    int s = idx >> 5, j = idx & 31;
    float inv = expf(-(float)j * (1.0f / 32.0f) * logf(10000.0f));
    float ang = (float)(s & 255) * inv;
    ct[idx] = cosf(ang);
    st[idx] = sinf(ang);
}

// ---------------------------------------------------------------------------
// RoPE apply (in-place on q and k inside qkv [2048][3072] bf16). grid 4096,256
// ---------------------------------------------------------------------------
__global__ __launch_bounds__(256) void rope_apply_k(ushort* __restrict__ qkv,
                                                    const float* __restrict__ ct,
                                                    const float* __restrict__ st) {
    int idx = blockIdx.x * 256 + threadIdx.x;  // < 2048*16*32
    int j = idx & 31;
    int head = (idx >> 5) & 15;
    int s = idx >> 9;
    size_t base = (size_t)s * 3072 + head * 64 + j;
    float c = ct[s * 32 + j], sn = st[s * 32 + j];
    float x1 = bf2f(qkv[base]), x2 = bf2f(qkv[base + 32]);
    qkv[base] = f2bf(x1 * c - x2 * sn);
    qkv[base + 32] = f2bf(x1 * sn + x2 * c);
    x1 = bf2f(qkv[base + 1024]); x2 = bf2f(qkv[base + 1056]);
    qkv[base + 1024] = f2bf(x1 * c - x2 * sn);
    qkv[base + 1056] = f2bf(x1 * sn + x2 * c);
}

// ---------------------------------------------------------------------------
// m97-style MFMA GEMM: C = A[M][K] @ Bt[N][K]^T, 128x128 tile, BK=32.
// OUT=0: bf16 store at row*ldc+col. OUT=2: fp32 store.
// OUT=3: bf16 partial store at blockIdx.z*zstr + row*ldc + col.
// grid (N/128, M/128, SK), 256 thr. SK splits K.
// ---------------------------------------------------------------------------
template <int OUT, int SK>
__global__ __launch_bounds__(256) void gemm_bt(const ushort* __restrict__ A, int lda,
                                               const ushort* __restrict__ Bt,
                                               void* __restrict__ Cp,
                                               int N, int K,
                                               int ldc, long zstr) {
    __shared__ ushort As[128 * 32];
    __shared__ ushort Bs[128 * 32];
    const int tid = threadIdx.x, wave = tid >> 6, lane = tid & 63;
    const int quad = lane >> 4, l15 = lane & 15;
    const int m0 = blockIdx.y * 128, n0 = blockIdx.x * 128;
    const int wm = wave & 1, wn = wave >> 1;
    const int Kc = K / SK;
    const int kbeg = blockIdx.z * Kc, kend = kbeg + Kc;
    float4v acc[4][4] = {};
    for (int k0 = kbeg; k0 < kend; k0 += 32) {
        __syncthreads();
#pragma unroll
        for (int h = 0; h < 2; ++h) {
            int c = wave * 2 + h;
            int mrow = c * 16 + (lane >> 2);
            int kb = (lane & 3) * 16;
            const char* ga = (const char*)A + ((size_t)(m0 + mrow) * lda + k0) * 2 + kb;
            __builtin_amdgcn_global_load_lds(
                (const __attribute__((address_space(1))) void*)ga,
                (__attribute__((address_space(3))) void*)((char*)As + c * 1024), 16, 0, 0);
            const char* gb = (const char*)Bt + ((size_t)(n0 + mrow) * K + k0) * 2 + kb;
            __builtin_amdgcn_global_load_lds(
                (const __attribute__((address_space(1))) void*)gb,
                (__attribute__((address_space(3))) void*)((char*)Bs + c * 1024), 16, 0, 0);
        }
        __syncthreads();
        short8 af[4], bf[4];
#pragma unroll
        for (int i = 0; i < 4; ++i)
            af[i] = *(const short8*)((const char*)As + (wm * 64 + i * 16 + l15) * 64 + quad * 16);
#pragma unroll
        for (int j = 0; j < 4; ++j)
            bf[j] = *(const short8*)((const char*)Bs + (wn * 64 + j * 16 + l15) * 64 + quad * 16);
#pragma unroll
        for (int i = 0; i < 4; ++i)
#pragma unroll
            for (int j = 0; j < 4; ++j)
                acc[i][j] = __builtin_amdgcn_mfma_f32_16x16x32_bf16(af[i], bf[j], acc[i][j], 0, 0, 0);
    }
    const size_t zoff = (OUT == 3) ? (size_t)blockIdx.z * zstr : 0;
#pragma unroll
    for (int i = 0; i < 4; ++i)
#pragma unroll
        for (int j = 0; j < 4; ++j)
#pragma unroll
            for (int r = 0; r < 4; ++r) {
                int row = m0 + wm * 64 + i * 16 + quad * 4 + r;
                int col = n0 + wn * 64 + j * 16 + l15;
                if (OUT == 0) {
                    ((ushort*)Cp)[(size_t)row * ldc + col] = f2bf(acc[i][j][r]);
                } else if (OUT == 2) {
                    ((float*)Cp)[(size_t)row * ldc + col] = acc[i][j][r];
                } else {
                    ((ushort*)Cp)[zoff + (size_t)row * ldc + col] = f2bf(acc[i][j][r]);
                }
            }
}

// ---------------------------------------------------------------------------
// Fused FFN-up GEMM: per block, t1 = hn@w1T-tile and t3 = hn@w3T-tile
// (same 128x128 tile coords), epilogue g = silu(t1)*t3 -> G [2048][4096] bf16.
// A = hn [2048][1024], W = [w1T|w3T] [8192][1024]. grid (4096/128=32, 16).
// 32 MFMA per K-iter per wave (vs 16 in gemm_bt).
// ---------------------------------------------------------------------------
__global__ __launch_bounds__(256) void gemm_w13(const ushort* __restrict__ A,
                                                const ushort* __restrict__ W,
                                                ushort* __restrict__ G) {
    __shared__ ushort As[128 * 32];
    __shared__ ushort B1[128 * 32];
    __shared__ ushort B3[128 * 32];
    const int tid = threadIdx.x, wave = tid >> 6, lane = tid & 63;
    const int quad = lane >> 4, l15 = lane & 15;
    const int m0 = blockIdx.y * 128, n0 = blockIdx.x * 128;
    const int wm = wave & 1, wn = wave >> 1;
    float4v acc1[4][4] = {};
    float4v acc3[4][4] = {};
    for (int k0 = 0; k0 < 1024; k0 += 32) {
        __syncthreads();
#pragma unroll
        for (int h = 0; h < 2; ++h) {
            int c = wave * 2 + h;
            int mrow = c * 16 + (lane >> 2);
            int kb = (lane & 3) * 16;
            const char* ga = (const char*)A + ((size_t)(m0 + mrow) * 1024 + k0) * 2 + kb;
            __builtin_amdgcn_global_load_lds(
                (const __attribute__((address_space(1))) void*)ga,
                (__attribute__((address_space(3))) void*)((char*)As + c * 1024), 16, 0, 0);
            const char* g1 = (const char*)W + ((size_t)(n0 + mrow) * 1024 + k0) * 2 + kb;
            __builtin_amdgcn_global_load_lds(
                (const __attribute__((address_space(1))) void*)g1,
                (__attribute__((address_space(3))) void*)((char*)B1 + c * 1024), 16, 0, 0);
            const char* g3 = (const char*)W + ((size_t)(4096 + n0 + mrow) * 1024 + k0) * 2 + kb;
            __builtin_amdgcn_global_load_lds(
                (const __attribute__((address_space(1))) void*)g3,
                (__attribute__((address_space(3))) void*)((char*)B3 + c * 1024), 16, 0, 0);
        }
        __syncthreads();
        short8 af[4], b1f[4], b3f[4];
#pragma unroll
        for (int i = 0; i < 4; ++i)
            af[i] = *(const short8*)((const char*)As + (wm * 64 + i * 16 + l15) * 64 + quad * 16);
#pragma unroll
        for (int j = 0; j < 4; ++j) {
            b1f[j] = *(const short8*)((const char*)B1 + (wn * 64 + j * 16 + l15) * 64 + quad * 16);
            b3f[j] = *(const short8*)((const char*)B3 + (wn * 64 + j * 16 + l15) * 64 + quad * 16);
        }
#pragma unroll
        for (int i = 0; i < 4; ++i)
#pragma unroll
            for (int j = 0; j < 4; ++j) {
                acc1[i][j] = __builtin_amdgcn_mfma_f32_16x16x32_bf16(af[i], b1f[j], acc1[i][j], 0, 0, 0);
                acc3[i][j] = __builtin_amdgcn_mfma_f32_16x16x32_bf16(af[i], b3f[j], acc3[i][j], 0, 0, 0);
            }
    }
#pragma unroll
    for (int i = 0; i < 4; ++i)
#pragma unroll
        for (int j = 0; j < 4; ++j)
#pragma unroll
            for (int r = 0; r < 4; ++r) {
                int row = m0 + wm * 64 + i * 16 + quad * 4 + r;
                int col = n0 + wn * 64 + j * 16 + l15;
                float x = acc1[i][j][r], y = acc3[i][j][r];
                float g = x / (1.0f + __expf(-x)) * y;
                G[(size_t)row * 4096 + col] = f2bf(g);
            }
}

// ---------------------------------------------------------------------------
// Attention: doc-blocked (256) windowed (|dq-dk|<128) softmax attention.
// qkv [2048][3072] bf16 (q|k|v, post-RoPE). o [2048][1024] bf16.
// grid 256 = (doc 8) x (head 16) x (qhalf 2); block 512 = 8 waves x 16 q rows.
// ---------------------------------------------------------------------------
__global__ __launch_bounds__(512) void attention_k(const ushort* __restrict__ qkv,
                                                   ushort* __restrict__ o) {
    __shared__ ushort Vt[64 * 264];     // V^T: [d][key], row stride 264
    __shared__ ushort Pc[8][16 * 40];   // per-wave P chunk [16 q][32 keys]
    const int tid = threadIdx.x, wave = tid >> 6, lane = tid & 63;
    const int quad = lane >> 4, l15 = lane & 15;
    const int doc = blockIdx.x >> 5, head = (blockIdx.x >> 1) & 15, qh = blockIdx.x & 1;
    const size_t S0 = (size_t)doc * 256;

    const ushort* vb = qkv + 2048 + head * 64;
    for (int i = tid; i < 256 * 64; i += 512) {
        int key = i >> 6, d = i & 63;
        Vt[d * 264 + key] = vb[(S0 + key) * 3072 + d];
    }

    const int q0 = qh * 128 + wave * 16;
    const ushort* qbase = qkv + head * 64;
    const ushort* kbase = qkv + 1024 + head * 64;
    short8 af0 = *(const short8*)&qbase[(S0 + q0 + l15) * 3072 + quad * 8];
    short8 af1 = *(const short8*)&qbase[(S0 + q0 + l15) * 3072 + 32 + quad * 8];

    float4v acc[16];
#pragma unroll
    for (int nt = 0; nt < 16; ++nt) {
        short8 b0 = *(const short8*)&kbase[(S0 + nt * 16 + l15) * 3072 + quad * 8];
        short8 b1 = *(const short8*)&kbase[(S0 + nt * 16 + l15) * 3072 + 32 + quad * 8];
        float4v a = {0.0f, 0.0f, 0.0f, 0.0f};
        a = __builtin_amdgcn_mfma_f32_16x16x32_bf16(af0, b0, a, 0, 0, 0);
        a = __builtin_amdgcn_mfma_f32_16x16x32_bf16(af1, b1, a, 0, 0, 0);
        acc[nt] = a;
    }

    float mx[4] = {-1e30f, -1e30f, -1e30f, -1e30f};
#pragma unroll
    for (int nt = 0; nt < 16; ++nt)
#pragma unroll
        for (int r = 0; r < 4; ++r) {
            int qp = q0 + quad * 4 + r;
            int kp = nt * 16 + l15;
            int dlt = qp - kp;
            bool ok = (dlt < 128) && (dlt > -128);
            float s = ok ? acc[nt][r] * 0.125f : -1e30f;
            acc[nt][r] = s;
            mx[r] = fmaxf(mx[r], s);
        }
#pragma unroll
    for (int r = 0; r < 4; ++r) {
        mx[r] = fmaxf(mx[r], __shfl_xor(mx[r], 1));
        mx[r] = fmaxf(mx[r], __shfl_xor(mx[r], 2));
        mx[r] = fmaxf(mx[r], __shfl_xor(mx[r], 4));
        mx[r] = fmaxf(mx[r], __shfl_xor(mx[r], 8));
    }
    float sum[4] = {0.0f, 0.0f, 0.0f, 0.0f};
#pragma unroll
    for (int nt = 0; nt < 16; ++nt)
#pragma unroll
        for (int r = 0; r < 4; ++r) {
            float p = __expf(acc[nt][r] - mx[r]);
            acc[nt][r] = p;
            sum[r] += p;
        }
    float inv[4];
#pragma unroll
    for (int r = 0; r < 4; ++r) {
        sum[r] += __shfl_xor(sum[r], 1);
        sum[r] += __shfl_xor(sum[r], 2);
        sum[r] += __shfl_xor(sum[r], 4);
        sum[r] += __shfl_xor(sum[r], 8);
        inv[r] = 1.0f / sum[r];
    }

    __syncthreads();  // Vt staged

    float4v oacc[4] = {};
    ushort* pcw = &Pc[wave][0];
#pragma unroll
    for (int ks = 0; ks < 8; ++ks) {
#pragma unroll
        for (int half = 0; half < 2; ++half) {
            int nt = ks * 2 + half;
#pragma unroll
            for (int r = 0; r < 4; ++r)
                pcw[(quad * 4 + r) * 40 + half * 16 + l15] = f2bf(acc[nt][r] * inv[r]);
        }
        __asm__ volatile("s_waitcnt lgkmcnt(0)" ::: "memory");
        short8 pf = *(const short8*)&pcw[l15 * 40 + quad * 8];
#pragma unroll
        for (int ntd = 0; ntd < 4; ++ntd) {
            short8 vf = *(const short8*)&Vt[(ntd * 16 + l15) * 264 + ks * 32 + quad * 8];
            oacc[ntd] = __builtin_amdgcn_mfma_f32_16x16x32_bf16(pf, vf, oacc[ntd], 0, 0, 0);
        }
    }
#pragma unroll
    for (int ntd = 0; ntd < 4; ++ntd)
#pragma unroll
        for (int r = 0; r < 4; ++r)
            o[(S0 + q0 + quad * 4 + r) * 1024 + head * 64 + ntd * 16 + l15] = f2bf(oacc[ntd][r]);
}

// ---------------------------------------------------------------------------
// Workspace (60.5 MB):
//   h fp32 0..8 | hn bf16 8..12 | big bf16 12..28 (qkv 12 MB / g 16 MB) |
//   pwo bf16 [4][2048][1024] 28..44 | wbuf 44..60 | cos/sin 60..60.5
// ---------------------------------------------------------------------------
extern "C" void kernel_launch(void* const* d_in, const int* in_sizes, int n_in,
                              void* d_out, int out_size, void* d_ws, size_t ws_size,
                              hipStream_t stream) {
    const float* x     = (const float*)d_in[0];
    const float* emb_w = (const float*)d_in[1];
    const float* emb_b = (const float*)d_in[2];
    const float* wq    = (const float*)d_in[3];
    const float* wk    = (const float*)d_in[4];
    const float* wv    = (const float*)d_in[5];
    const float* wo    = (const float*)d_in[6];
    const float* anw   = (const float*)d_in[7];
    const float* fnw   = (const float*)d_in[8];
    const float* w1    = (const float*)d_in[9];
    const float* w2    = (const float*)d_in[10];
    const float* w3    = (const float*)d_in[11];
    const float* onw   = (const float*)d_in[12];
    const float* ow    = (const float*)d_in[13];

    char* ws = (char*)d_ws;
    float*  h    = (float*)(ws);
    ushort* hn   = (ushort*)(ws + (8u << 20));
    ushort* big  = (ushort*)(ws + (12u << 20));
    ushort* pwo  = (ushort*)(ws + (28u << 20));
    ushort* wbuf = (ushort*)(ws + (44u << 20));
    float*  cosT = (float*)(ws + (60u << 20));
    float*  sinT = (float*)(ws + (60u << 20) + (256u << 10));

    const long ZSTR = (long)2048 * 1024;
    dim3 b256(256);
    rope_table_k<<<256, b256, 0, stream>>>(cosT, sinT);
    embed_k<<<dim3(4, 2048), b256, 0, stream>>>(x, emb_w, emb_b, h);
    rmsnorm_k<<<2048, b256, 0, stream>>>(h, anw, hn);

    for (int l = 0; l < 4; ++l) {
        const float* wq_l = wq + (size_t)l * 1024 * 1024;
        const float* wk_l = wk + (size_t)l * 1024 * 1024;
        const float* wv_l = wv + (size_t)l * 1024 * 1024;
        const float* wo_l = wo + (size_t)l * 1024 * 1024;
        const float* w1_l = w1 + (size_t)l * 1024 * 4096;
        const float* w2_l = w2 + (size_t)l * 4096 * 1024;
        const float* w3_l = w3 + (size_t)l * 1024 * 4096;

        // ---- attention block ----
        transpose4_f2b<<<dim3(16, 16, 4), b256, 0, stream>>>(wq_l, wk_l, wv_l, wo_l,
                                                             wbuf, 1024, 1024);
        gemm_bt<0, 1><<<dim3(24, 16), b256, 0, stream>>>(hn, 1024, wbuf, big,
                                                         3072, 1024, 3072, 0);
        rope_apply_k<<<4096, b256, 0, stream>>>(big, cosT, sinT);
        attention_k<<<256, dim3(512), 0, stream>>>(big, hn);

        gemm_bt<3, 4><<<dim3(8, 16, 4), b256, 0, stream>>>(hn, 1024,
            wbuf + (size_t)3 * 1024 * 1024, pwo, 1024, 1024, 1024, ZSTR);
        reduce_rms_k<<<2048, b256, 0, stream>>>(pwo, h, fnw + (size_t)l * 1024, hn);

        // ---- FFN block ----
        transpose4_f2b<<<dim3(64, 16, 2), b256, 0, stream>>>(w1_l, w3_l, w1_l, w1_l,
                                                             wbuf, 1024, 4096);
        gemm_w13<<<dim3(32, 16), b256, 0, stream>>>(hn, wbuf, big);

        transpose4_f2b<<<dim3(16, 64, 1), b256, 0, stream>>>(w2_l, w2_l, w2_l, w2_l,
                                                             wbuf, 4096, 1024);
        gemm_bt<3, 4><<<dim3(8, 16, 4), b256, 0, stream>>>(big, 4096, wbuf, pwo,
                                                           1024, 4096, 1024, ZSTR);
        const float* nw = (l < 3) ? (anw + (size_t)(l + 1) * 1024) : onw;
        reduce_rms_k<<<2048, b256, 0, stream>>>(pwo, h, nw, hn);
    }

    transpose4_f2b<<<dim3(2, 16, 1), b256, 0, stream>>>(ow, ow, ow, ow, wbuf, 1024, 128);
    gemm_bt<2, 1><<<dim3(1, 16), b256, 0, stream>>>(hn, 1024, wbuf, d_out,
                                                    128, 1024, 128, 0);
}

// Round 7
// 1001.403 us; speedup vs baseline: 1.0856x; 1.0856x over previous
//
#include <hip/hip_runtime.h>
#include <hip/hip_bf16.h>

typedef __attribute__((ext_vector_type(8))) short short8;
typedef __attribute__((ext_vector_type(4))) float float4v;

__device__ __forceinline__ float bf2f(ushort u) {
    union { unsigned int i; float f; } x; x.i = ((unsigned int)u) << 16; return x.f;
}
__device__ __forceinline__ ushort f2bf(float f) {
    union { float f; unsigned int i; } x; x.f = f;
    unsigned int i = x.i;
    unsigned int r = (i + 0x7fffu + ((i >> 16) & 1u)) >> 16;
    return (ushort)r;
}

// ---------------------------------------------------------------------------
// Transpose+cast: src [K][N] fp32 -> dst [N][K] bf16. grid (N/64, K/64, NSRC).
// ---------------------------------------------------------------------------
__global__ __launch_bounds__(256) void transpose4_f2b(const float* __restrict__ s0,
                                                      const float* __restrict__ s1,
                                                      const float* __restrict__ s2,
                                                      const float* __restrict__ s3,
                                                      ushort* __restrict__ dst,
                                                      int K, int N) {
    __shared__ ushort tile[64][68];
    const float* srcs[4] = {s0, s1, s2, s3};
    const float* src = srcs[blockIdx.z];
    ushort* d = dst + (size_t)blockIdx.z * K * N;
    const int t = threadIdx.x;
    const int n0 = blockIdx.x * 64, k0 = blockIdx.y * 64;
    const int tr = t >> 4, tc = (t & 15) * 4;
#pragma unroll
    for (int i = 0; i < 4; ++i) {
        int row = tr + i * 16;
        float4 v = *(const float4*)&src[(size_t)(k0 + row) * N + n0 + tc];
        tile[row][tc + 0] = f2bf(v.x);
        tile[row][tc + 1] = f2bf(v.y);
        tile[row][tc + 2] = f2bf(v.z);
        tile[row][tc + 3] = f2bf(v.w);
    }
    __syncthreads();
#pragma unroll
    for (int i = 0; i < 4; ++i) {
        int n = tr + i * 16;
        ushort4 v;
        v.x = tile[tc + 0][n]; v.y = tile[tc + 1][n];
        v.z = tile[tc + 2][n]; v.w = tile[tc + 3][n];
        *(ushort4*)&d[(size_t)(n0 + n) * K + k0 + tc] = v;
    }
}

// ---------------------------------------------------------------------------
// Embed: h[2048][1024] fp32 = x[2048][64] @ emb_w[64][1024] + emb_b (all fp32)
// ---------------------------------------------------------------------------
__global__ __launch_bounds__(256) void embed_k(const float* __restrict__ x,
                                               const float* __restrict__ w,
                                               const float* __restrict__ b,
                                               float* __restrict__ h) {
    const int row = blockIdx.y;
    const int col = blockIdx.x * 256 + threadIdx.x;
    float acc = b[col];
#pragma unroll 8
    for (int k = 0; k < 64; ++k)
        acc += x[row * 64 + k] * w[k * 1024 + col];
    h[(size_t)row * 1024 + col] = acc;
}

// ---------------------------------------------------------------------------
// RMSNorm: fp32 h row, fp32 weight, bf16 out. grid 2048, 256 thr
// ---------------------------------------------------------------------------
__global__ __launch_bounds__(256) void rmsnorm_k(const float* __restrict__ h,
                                                 const float* __restrict__ w,
                                                 ushort* __restrict__ out) {
    const int row = blockIdx.x, t = threadIdx.x;
    float4 v = ((const float4*)(h + (size_t)row * 1024))[t];
    float ss = v.x * v.x + v.y * v.y + v.z * v.z + v.w * v.w;
#pragma unroll
    for (int off = 32; off > 0; off >>= 1) ss += __shfl_down(ss, off);
    __shared__ float red[4];
    if ((t & 63) == 0) red[t >> 6] = ss;
    __syncthreads();
    float inv = rsqrtf((red[0] + red[1] + red[2] + red[3]) * (1.0f / 1024.0f) + 1e-5f);
    float4 wv = ((const float4*)w)[t];
    ushort4 ov;
    ov.x = f2bf(v.x * inv * wv.x);
    ov.y = f2bf(v.y * inv * wv.y);
    ov.z = f2bf(v.z * inv * wv.z);
    ov.w = f2bf(v.w * inv * wv.w);
    *(ushort4*)&out[(size_t)row * 1024 + t * 4] = ov;
}

// ---------------------------------------------------------------------------
// Fused split-K reduce + residual add + RMSNorm.
// p: bf16 partials [4][2048][1024]. h += sum_z p; out = rmsnorm(h)*w (bf16).
// grid 2048, 256 thr.
// ---------------------------------------------------------------------------
__global__ __launch_bounds__(256) void reduce_rms_k(const ushort* __restrict__ p,
                                                    float* __restrict__ h,
                                                    const float* __restrict__ w,
                                                    ushort* __restrict__ out) {
    const int row = blockIdx.x, t = threadIdx.x;
    const int c = t * 4;
    size_t base = (size_t)row * 1024 + c;
    float a0 = 0, a1 = 0, a2 = 0, a3 = 0;
#pragma unroll
    for (int z = 0; z < 4; ++z) {
        ushort4 v = *(const ushort4*)&p[base + (size_t)z * 2048 * 1024];
        a0 += bf2f(v.x); a1 += bf2f(v.y); a2 += bf2f(v.z); a3 += bf2f(v.w);
    }
    float4 cur = *(float4*)&h[base];
    cur.x += a0; cur.y += a1; cur.z += a2; cur.w += a3;
    *(float4*)&h[base] = cur;
    float ss = cur.x * cur.x + cur.y * cur.y + cur.z * cur.z + cur.w * cur.w;
#pragma unroll
    for (int off = 32; off > 0; off >>= 1) ss += __shfl_down(ss, off);
    __shared__ float red[4];
    if ((t & 63) == 0) red[t >> 6] = ss;
    __syncthreads();
    float inv = rsqrtf((red[0] + red[1] + red[2] + red[3]) * (1.0f / 1024.0f) + 1e-5f);
    float4 wv = ((const float4*)w)[t];
    ushort4 ov;
    ov.x = f2bf(cur.x * inv * wv.x);
    ov.y = f2bf(cur.y * inv * wv.y);
    ov.z = f2bf(cur.z * inv * wv.z);
    ov.w = f2bf(cur.w * inv * wv.w);
    *(ushort4*)&out[base] = ov;
}

// ---------------------------------------------------------------------------
// RoPE tables: cos/sin [2048][32] fp32. grid 256, 256 thr
// ---------------------------------------------------------------------------
__global__ __launch_bounds__(256) void rope_table_k(float* __restrict__ ct,
                                                    float* __restrict__ st) {
    int idx = blockIdx.x * 256 + threadIdx.x;  // < 65536
    int s = idx >> 5, j = idx & 31;
    float inv = expf(-(float)j * (1.0f / 32.0f) * logf(10000.0f));
    float ang = (float)(s & 255) * inv;
    ct[idx] = cosf(ang);
    st[idx] = sinf(ang);
}

// ---------------------------------------------------------------------------
// QKV GEMM with fused RoPE epilogue.
// C[2048][3072] = A[2048][1024] @ Wt[3072][1024]^T. grid (24,16), 256 thr.
// Blocks with n0 < 2048 (q,k cols) rotate pairs (j=0,j=2) and (j=1,j=3):
// within a 64-col head window, thread's cols are l15, l15+16, l15+32, l15+48.
// ---------------------------------------------------------------------------
__global__ __launch_bounds__(256) void gemm_qkv(const ushort* __restrict__ A,
                                                const ushort* __restrict__ Wt,
                                                ushort* __restrict__ C,
                                                const float* __restrict__ ct,
                                                const float* __restrict__ st) {
    __shared__ ushort As[128 * 32];
    __shared__ ushort Bs[128 * 32];
    const int tid = threadIdx.x, wave = tid >> 6, lane = tid & 63;
    const int quad = lane >> 4, l15 = lane & 15;
    const int m0 = blockIdx.y * 128, n0 = blockIdx.x * 128;
    const int wm = wave & 1, wn = wave >> 1;
    float4v acc[4][4] = {};
    for (int k0 = 0; k0 < 1024; k0 += 32) {
        __syncthreads();
#pragma unroll
        for (int h = 0; h < 2; ++h) {
            int c = wave * 2 + h;
            int mrow = c * 16 + (lane >> 2);
            int kb = (lane & 3) * 16;
            const char* ga = (const char*)A + ((size_t)(m0 + mrow) * 1024 + k0) * 2 + kb;
            __builtin_amdgcn_global_load_lds(
                (const __attribute__((address_space(1))) void*)ga,
                (__attribute__((address_space(3))) void*)((char*)As + c * 1024), 16, 0, 0);
            const char* gb = (const char*)Wt + ((size_t)(n0 + mrow) * 1024 + k0) * 2 + kb;
            __builtin_amdgcn_global_load_lds(
                (const __attribute__((address_space(1))) void*)gb,
                (__attribute__((address_space(3))) void*)((char*)Bs + c * 1024), 16, 0, 0);
        }
        __syncthreads();
        short8 af[4], bf[4];
#pragma unroll
        for (int i = 0; i < 4; ++i)
            af[i] = *(const short8*)((const char*)As + (wm * 64 + i * 16 + l15) * 64 + quad * 16);
#pragma unroll
        for (int j = 0; j < 4; ++j)
            bf[j] = *(const short8*)((const char*)Bs + (wn * 64 + j * 16 + l15) * 64 + quad * 16);
#pragma unroll
        for (int i = 0; i < 4; ++i)
#pragma unroll
            for (int j = 0; j < 4; ++j)
                acc[i][j] = __builtin_amdgcn_mfma_f32_16x16x32_bf16(af[i], bf[j], acc[i][j], 0, 0, 0);
    }
    const int colb = n0 + wn * 64;  // 64-aligned head window base
    if (blockIdx.x < 16) {
        // q,k region: RoPE
#pragma unroll
        for (int i = 0; i < 4; ++i)
#pragma unroll
            for (int r = 0; r < 4; ++r) {
                int row = m0 + wm * 64 + i * 16 + quad * 4 + r;
                size_t ob = (size_t)row * 3072 + colb;
                float c0 = ct[row * 32 + l15], s0 = st[row * 32 + l15];
                float x1 = acc[i][0][r], x2 = acc[i][2][r];
                C[ob + l15]      = f2bf(x1 * c0 - x2 * s0);
                C[ob + 32 + l15] = f2bf(x1 * s0 + x2 * c0);
                float c1 = ct[row * 32 + 16 + l15], s1 = st[row * 32 + 16 + l15];
                float y1 = acc[i][1][r], y2 = acc[i][3][r];
                C[ob + 16 + l15] = f2bf(y1 * c1 - y2 * s1);
                C[ob + 48 + l15] = f2bf(y1 * s1 + y2 * c1);
            }
    } else {
#pragma unroll
        for (int i = 0; i < 4; ++i)
#pragma unroll
            for (int j = 0; j < 4; ++j)
#pragma unroll
                for (int r = 0; r < 4; ++r) {
                    int row = m0 + wm * 64 + i * 16 + quad * 4 + r;
                    C[(size_t)row * 3072 + colb + j * 16 + l15] = f2bf(acc[i][j][r]);
                }
    }
}

// ---------------------------------------------------------------------------
// m97-style MFMA GEMM: C = A[M][K] @ Bt[N][K]^T, 128x128 tile, BK=32.
// OUT=0: bf16 store at row*ldc+col. OUT=2: fp32 store.
// OUT=3: bf16 partial store at blockIdx.z*zstr + row*ldc + col.
// grid (N/128, M/128, SK), 256 thr. SK splits K.
// ---------------------------------------------------------------------------
template <int OUT, int SK>
__global__ __launch_bounds__(256) void gemm_bt(const ushort* __restrict__ A, int lda,
                                               const ushort* __restrict__ Bt,
                                               void* __restrict__ Cp,
                                               int N, int K,
                                               int ldc, long zstr) {
    __shared__ ushort As[128 * 32];
    __shared__ ushort Bs[128 * 32];
    const int tid = threadIdx.x, wave = tid >> 6, lane = tid & 63;
    const int quad = lane >> 4, l15 = lane & 15;
    const int m0 = blockIdx.y * 128, n0 = blockIdx.x * 128;
    const int wm = wave & 1, wn = wave >> 1;
    const int Kc = K / SK;
    const int kbeg = blockIdx.z * Kc, kend = kbeg + Kc;
    float4v acc[4][4] = {};
    for (int k0 = kbeg; k0 < kend; k0 += 32) {
        __syncthreads();
#pragma unroll
        for (int h = 0; h < 2; ++h) {
            int c = wave * 2 + h;
            int mrow = c * 16 + (lane >> 2);
            int kb = (lane & 3) * 16;
            const char* ga = (const char*)A + ((size_t)(m0 + mrow) * lda + k0) * 2 + kb;
            __builtin_amdgcn_global_load_lds(
                (const __attribute__((address_space(1))) void*)ga,
                (__attribute__((address_space(3))) void*)((char*)As + c * 1024), 16, 0, 0);
            const char* gb = (const char*)Bt + ((size_t)(n0 + mrow) * K + k0) * 2 + kb;
            __builtin_amdgcn_global_load_lds(
                (const __attribute__((address_space(1))) void*)gb,
                (__attribute__((address_space(3))) void*)((char*)Bs + c * 1024), 16, 0, 0);
        }
        __syncthreads();
        short8 af[4], bf[4];
#pragma unroll
        for (int i = 0; i < 4; ++i)
            af[i] = *(const short8*)((const char*)As + (wm * 64 + i * 16 + l15) * 64 + quad * 16);
#pragma unroll
        for (int j = 0; j < 4; ++j)
            bf[j] = *(const short8*)((const char*)Bs + (wn * 64 + j * 16 + l15) * 64 + quad * 16);
#pragma unroll
        for (int i = 0; i < 4; ++i)
#pragma unroll
            for (int j = 0; j < 4; ++j)
                acc[i][j] = __builtin_amdgcn_mfma_f32_16x16x32_bf16(af[i], bf[j], acc[i][j], 0, 0, 0);
    }
    const size_t zoff = (OUT == 3) ? (size_t)blockIdx.z * zstr : 0;
#pragma unroll
    for (int i = 0; i < 4; ++i)
#pragma unroll
        for (int j = 0; j < 4; ++j)
#pragma unroll
            for (int r = 0; r < 4; ++r) {
                int row = m0 + wm * 64 + i * 16 + quad * 4 + r;
                int col = n0 + wn * 64 + j * 16 + l15;
                if (OUT == 0) {
                    ((ushort*)Cp)[(size_t)row * ldc + col] = f2bf(acc[i][j][r]);
                } else if (OUT == 2) {
                    ((float*)Cp)[(size_t)row * ldc + col] = acc[i][j][r];
                } else {
                    ((ushort*)Cp)[zoff + (size_t)row * ldc + col] = f2bf(acc[i][j][r]);
                }
            }
}

// ---------------------------------------------------------------------------
// Fused FFN-up GEMM, constant-register version: block computes 128x64 tiles
// of BOTH t1 and t3 (same cols), epilogue g = silu(t1)*t3 -> G [2048][4096].
// A = hn [2048][1024], W = [w1T|w3T] [8192][1024]. grid (64, 16), 256 thr.
// Accumulator budget = 16 tiles/wave, same as gemm_bt (VGPR ~equal).
// ---------------------------------------------------------------------------
__global__ __launch_bounds__(256) void gemm_w13(const ushort* __restrict__ A,
                                                const ushort* __restrict__ W,
                                                ushort* __restrict__ G) {
    __shared__ ushort As[128 * 32];  // 8 KB
    __shared__ ushort B1[64 * 32];   // 4 KB
    __shared__ ushort B3[64 * 32];   // 4 KB
    const int tid = threadIdx.x, wave = tid >> 6, lane = tid & 63;
    const int quad = lane >> 4, l15 = lane & 15;
    const int m0 = blockIdx.y * 128, n0 = blockIdx.x * 64;
    const int wm = wave & 1, wn = wave >> 1;  // wn in 0..1: 32-col half
    float4v acc1[4][2] = {};
    float4v acc3[4][2] = {};
    for (int k0 = 0; k0 < 1024; k0 += 32) {
        __syncthreads();
#pragma unroll
        for (int h = 0; h < 4; ++h) {
            int c = wave * 4 + h;  // 0..15
            int mrow = lane >> 2;
            int kb = (lane & 3) * 16;
            const char* ga;
            char* ldst;
            if (c < 8) {
                ga = (const char*)A + ((size_t)(m0 + c * 16 + mrow) * 1024 + k0) * 2 + kb;
                ldst = (char*)As + c * 1024;
            } else if (c < 12) {
                int cc = c - 8;
                ga = (const char*)W + ((size_t)(n0 + cc * 16 + mrow) * 1024 + k0) * 2 + kb;
                ldst = (char*)B1 + cc * 1024;
            } else {
                int cc = c - 12;
                ga = (const char*)W + ((size_t)(4096 + n0 + cc * 16 + mrow) * 1024 + k0) * 2 + kb;
                ldst = (char*)B3 + cc * 1024;
            }
            __builtin_amdgcn_global_load_lds(
                (const __attribute__((address_space(1))) void*)ga,
                (__attribute__((address_space(3))) void*)ldst, 16, 0, 0);
        }
        __syncthreads();
        short8 af[4], b1f[2], b3f[2];
#pragma unroll
        for (int i = 0; i < 4; ++i)
            af[i] = *(const short8*)((const char*)As + (wm * 64 + i * 16 + l15) * 64 + quad * 16);
#pragma unroll
        for (int j = 0; j < 2; ++j) {
            b1f[j] = *(const short8*)((const char*)B1 + (wn * 32 + j * 16 + l15) * 64 + quad * 16);
            b3f[j] = *(const short8*)((const char*)B3 + (wn * 32 + j * 16 + l15) * 64 + quad * 16);
        }
#pragma unroll
        for (int i = 0; i < 4; ++i)
#pragma unroll
            for (int j = 0; j < 2; ++j) {
                acc1[i][j] = __builtin_amdgcn_mfma_f32_16x16x32_bf16(af[i], b1f[j], acc1[i][j], 0, 0, 0);
                acc3[i][j] = __builtin_amdgcn_mfma_f32_16x16x32_bf16(af[i], b3f[j], acc3[i][j], 0, 0, 0);
            }
    }
#pragma unroll
    for (int i = 0; i < 4; ++i)
#pragma unroll
        for (int j = 0; j < 2; ++j)
#pragma unroll
            for (int r = 0; r < 4; ++r) {
                int row = m0 + wm * 64 + i * 16 + quad * 4 + r;
                int col = n0 + wn * 32 + j * 16 + l15;
                float x = acc1[i][j][r], y = acc3[i][j][r];
                float g = x / (1.0f + __expf(-x)) * y;
                G[(size_t)row * 4096 + col] = f2bf(g);
            }
}

// ---------------------------------------------------------------------------
// Attention: doc-blocked (256) windowed (|dq-dk|<128) softmax attention.
// qkv [2048][3072] bf16 (q|k|v, post-RoPE). o [2048][1024] bf16.
// grid 256 = (doc 8) x (head 16) x (qhalf 2); block 512 = 8 waves x 16 q rows.
// ---------------------------------------------------------------------------
__global__ __launch_bounds__(512) void attention_k(const ushort* __restrict__ qkv,
                                                   ushort* __restrict__ o) {
    __shared__ ushort Vt[64 * 264];     // V^T: [d][key], row stride 264
    __shared__ ushort Pc[8][16 * 40];   // per-wave P chunk [16 q][32 keys]
    const int tid = threadIdx.x, wave = tid >> 6, lane = tid & 63;
    const int quad = lane >> 4, l15 = lane & 15;
    const int doc = blockIdx.x >> 5, head = (blockIdx.x >> 1) & 15, qh = blockIdx.x & 1;
    const size_t S0 = (size_t)doc * 256;

    const ushort* vb = qkv + 2048 + head * 64;
    for (int i = tid; i < 256 * 64; i += 512) {
        int key = i >> 6, d = i & 63;
        Vt[d * 264 + key] = vb[(S0 + key) * 3072 + d];
    }

    const int q0 = qh * 128 + wave * 16;
    const ushort* qbase = qkv + head * 64;
    const ushort* kbase = qkv + 1024 + head * 64;
    short8 af0 = *(const short8*)&qbase[(S0 + q0 + l15) * 3072 + quad * 8];
    short8 af1 = *(const short8*)&qbase[(S0 + q0 + l15) * 3072 + 32 + quad * 8];

    float4v acc[16];
#pragma unroll
    for (int nt = 0; nt < 16; ++nt) {
        short8 b0 = *(const short8*)&kbase[(S0 + nt * 16 + l15) * 3072 + quad * 8];
        short8 b1 = *(const short8*)&kbase[(S0 + nt * 16 + l15) * 3072 + 32 + quad * 8];
        float4v a = {0.0f, 0.0f, 0.0f, 0.0f};
        a = __builtin_amdgcn_mfma_f32_16x16x32_bf16(af0, b0, a, 0, 0, 0);
        a = __builtin_amdgcn_mfma_f32_16x16x32_bf16(af1, b1, a, 0, 0, 0);
        acc[nt] = a;
    }

    float mx[4] = {-1e30f, -1e30f, -1e30f, -1e30f};
#pragma unroll
    for (int nt = 0; nt < 16; ++nt)
#pragma unroll
        for (int r = 0; r < 4; ++r) {
            int qp = q0 + quad * 4 + r;
            int kp = nt * 16 + l15;
            int dlt = qp - kp;
            bool ok = (dlt < 128) && (dlt > -128);
            float s = ok ? acc[nt][r] * 0.125f : -1e30f;
            acc[nt][r] = s;
            mx[r] = fmaxf(mx[r], s);
        }
#pragma unroll
    for (int r = 0; r < 4; ++r) {
        mx[r] = fmaxf(mx[r], __shfl_xor(mx[r], 1));
        mx[r] = fmaxf(mx[r], __shfl_xor(mx[r], 2));
        mx[r] = fmaxf(mx[r], __shfl_xor(mx[r], 4));
        mx[r] = fmaxf(mx[r], __shfl_xor(mx[r], 8));
    }
    float sum[4] = {0.0f, 0.0f, 0.0f, 0.0f};
#pragma unroll
    for (int nt = 0; nt < 16; ++nt)
#pragma unroll
        for (int r = 0; r < 4; ++r) {
            float p = __expf(acc[nt][r] - mx[r]);
            acc[nt][r] = p;
            sum[r] += p;
        }
    float inv[4];
#pragma unroll
    for (int r = 0; r < 4; ++r) {
        sum[r] += __shfl_xor(sum[r], 1);
        sum[r] += __shfl_xor(sum[r], 2);
        sum[r] += __shfl_xor(sum[r], 4);
        sum[r] += __shfl_xor(sum[r], 8);
        inv[r] = 1.0f / sum[r];
    }

    __syncthreads();  // Vt staged

    float4v oacc[4] = {};
    ushort* pcw = &Pc[wave][0];
#pragma unroll
    for (int ks = 0; ks < 8; ++ks) {
#pragma unroll
        for (int half = 0; half < 2; ++half) {
            int nt = ks * 2 + half;
#pragma unroll
            for (int r = 0; r < 4; ++r)
                pcw[(quad * 4 + r) * 40 + half * 16 + l15] = f2bf(acc[nt][r] * inv[r]);
        }
        __asm__ volatile("s_waitcnt lgkmcnt(0)" ::: "memory");
        short8 pf = *(const short8*)&pcw[l15 * 40 + quad * 8];
#pragma unroll
        for (int ntd = 0; ntd < 4; ++ntd) {
            short8 vf = *(const short8*)&Vt[(ntd * 16 + l15) * 264 + ks * 32 + quad * 8];
            oacc[ntd] = __builtin_amdgcn_mfma_f32_16x16x32_bf16(pf, vf, oacc[ntd], 0, 0, 0);
        }
    }
#pragma unroll
    for (int ntd = 0; ntd < 4; ++ntd)
#pragma unroll
        for (int r = 0; r < 4; ++r)
            o[(S0 + q0 + quad * 4 + r) * 1024 + head * 64 + ntd * 16 + l15] = f2bf(oacc[ntd][r]);
}

// ---------------------------------------------------------------------------
// Workspace (60.5 MB):
//   h fp32 0..8 | hn bf16 8..12 | big bf16 12..28 (qkv 12 MB / g 16 MB) |
//   pwo bf16 [4][2048][1024] 28..44 | wbuf 44..60 | cos/sin 60..60.5
// ---------------------------------------------------------------------------
extern "C" void kernel_launch(void* const* d_in, const int* in_sizes, int n_in,
                              void* d_out, int out_size, void* d_ws, size_t ws_size,
                              hipStream_t stream) {
    const float* x     = (const float*)d_in[0];
    const float* emb_w = (const float*)d_in[1];
    const float* emb_b = (const float*)d_in[2];
    const float* wq    = (const float*)d_in[3];
    const float* wk    = (const float*)d_in[4];
    const float* wv    = (const float*)d_in[5];
    const float* wo    = (const float*)d_in[6];
    const float* anw   = (const float*)d_in[7];
    const float* fnw   = (const float*)d_in[8];
    const float* w1    = (const float*)d_in[9];
    const float* w2    = (const float*)d_in[10];
    const float* w3    = (const float*)d_in[11];
    const float* onw   = (const float*)d_in[12];
    const float* ow    = (const float*)d_in[13];

    char* ws = (char*)d_ws;
    float*  h    = (float*)(ws);
    ushort* hn   = (ushort*)(ws + (8u << 20));
    ushort* big  = (ushort*)(ws + (12u << 20));
    ushort* pwo  = (ushort*)(ws + (28u << 20));
    ushort* wbuf = (ushort*)(ws + (44u << 20));
    float*  cosT = (float*)(ws + (60u << 20));
    float*  sinT = (float*)(ws + (60u << 20) + (256u << 10));

    const long ZSTR = (long)2048 * 1024;
    dim3 b256(256);
    rope_table_k<<<256, b256, 0, stream>>>(cosT, sinT);
    embed_k<<<dim3(4, 2048), b256, 0, stream>>>(x, emb_w, emb_b, h);
    rmsnorm_k<<<2048, b256, 0, stream>>>(h, anw, hn);

    for (int l = 0; l < 4; ++l) {
        const float* wq_l = wq + (size_t)l * 1024 * 1024;
        const float* wk_l = wk + (size_t)l * 1024 * 1024;
        const float* wv_l = wv + (size_t)l * 1024 * 1024;
        const float* wo_l = wo + (size_t)l * 1024 * 1024;
        const float* w1_l = w1 + (size_t)l * 1024 * 4096;
        const float* w2_l = w2 + (size_t)l * 4096 * 1024;
        const float* w3_l = w3 + (size_t)l * 1024 * 4096;

        // ---- attention block ----
        transpose4_f2b<<<dim3(16, 16, 4), b256, 0, stream>>>(wq_l, wk_l, wv_l, wo_l,
                                                             wbuf, 1024, 1024);
        gemm_qkv<<<dim3(24, 16), b256, 0, stream>>>(hn, wbuf, big, cosT, sinT);
        attention_k<<<256, dim3(512), 0, stream>>>(big, hn);

        gemm_bt<3, 4><<<dim3(8, 16, 4), b256, 0, stream>>>(hn, 1024,
            wbuf + (size_t)3 * 1024 * 1024, pwo, 1024, 1024, 1024, ZSTR);
        reduce_rms_k<<<2048, b256, 0, stream>>>(pwo, h, fnw + (size_t)l * 1024, hn);

        // ---- FFN block ----
        transpose4_f2b<<<dim3(64, 16, 2), b256, 0, stream>>>(w1_l, w3_l, w1_l, w1_l,
                                                             wbuf, 1024, 4096);
        gemm_w13<<<dim3(64, 16), b256, 0, stream>>>(hn, wbuf, big);

        transpose4_f2b<<<dim3(16, 64, 1), b256, 0, stream>>>(w2_l, w2_l, w2_l, w2_l,
                                                             wbuf, 4096, 1024);
        gemm_bt<3, 4><<<dim3(8, 16, 4), b256, 0, stream>>>(big, 4096, wbuf, pwo,
                                                           1024, 4096, 1024, ZSTR);
        const float* nw = (l < 3) ? (anw + (size_t)(l + 1) * 1024) : onw;
        reduce_rms_k<<<2048, b256, 0, stream>>>(pwo, h, nw, hn);
    }

    transpose4_f2b<<<dim3(2, 16, 1), b256, 0, stream>>>(ow, ow, ow, ow, wbuf, 1024, 128);
    gemm_bt<2, 1><<<dim3(1, 16), b256, 0, stream>>>(hn, 1024, wbuf, d_out,
                                                    128, 1024, 128, 0);
}